// Round 2
// baseline (336.182 us; speedup 1.0000x reference)
//
#include <hip/hip_runtime.h>
#include <stdint.h>

// Problem dims
#define BB   512
#define NNN  64
#define HHH  256
#define BN_  32768   // B*N
#define H2_  512
#define H3_  768

typedef unsigned short u16;
typedef unsigned int   u32;
typedef __attribute__((ext_vector_type(8))) short bf16x8;   // 8 bf16 in 4 VGPRs
typedef __attribute__((ext_vector_type(4))) float f32x4;

__device__ __forceinline__ u16 f2bf(float f) {
  union { float f; u32 u; } x; x.f = f;
  return (u16)((x.u + 0x7fffu + ((x.u >> 16) & 1u)) >> 16);  // RNE
}
__device__ __forceinline__ float bf2f(u16 v) {
  union { u32 u; float f; } x; x.u = ((u32)v) << 16; return x.f;
}
// async global->LDS, 16B per lane; LDS dest = wave-uniform base + lane*16
__device__ __forceinline__ void async16(const void* g, void* l) {
  __builtin_amdgcn_global_load_lds(
      (const __attribute__((address_space(1))) u32*)(uintptr_t)g,
      (__attribute__((address_space(3))) u32*)(uintptr_t)l, 16, 0, 0);
}
__device__ __forceinline__ float sigmoidf_(float x) { return 1.0f / (1.0f + __expf(-x)); }

// ---------------------------------------------------------------- K0: f32 weights -> bf16 wcat
// wcat layout (elems): [W_in 65536 | W_out 65536 | w_ih 393216 | w_hh 196608] total 720896
__global__ __launch_bounds__(256) void k_convert(const float* __restrict__ W_in,
                                                 const float* __restrict__ W_out,
                                                 const float* __restrict__ w_ih,
                                                 const float* __restrict__ w_hh,
                                                 u16* __restrict__ wcat) {
  int i = blockIdx.x * 256 + threadIdx.x;
  const float* src; int off;
  if (i < 65536)       { src = W_in;  off = i; }
  else if (i < 131072) { src = W_out; off = i - 65536; }
  else if (i < 524288) { src = w_ih;  off = i - 131072; }
  else                 { src = w_hh;  off = i - 524288; }
  wcat[i] = f2bf(src[off]);
}

// ---------------------------------------------------------------- K1: gather + L2 norm
// h[row] = emb[idx[row]] / (||.||2 + 1e-12), f32 in -> bf16 out. One wave per row.
__global__ __launch_bounds__(256) void k_gather_norm(const int* __restrict__ idx,
                                                     const float* __restrict__ emb,
                                                     u16* __restrict__ h) {
  int row  = blockIdx.x * 4 + (threadIdx.x >> 6);
  int lane = threadIdx.x & 63;
  int e = idx[row];
  float4 v = *(const float4*)(emb + (size_t)e * HHH + lane * 4);
  float s = v.x * v.x + v.y * v.y + v.z * v.z + v.w * v.w;
  for (int off = 32; off; off >>= 1) s += __shfl_xor(s, off, 64);
  float sc = 1.0f / (sqrtf(s) + 1e-12f);
  ushort4 o;
  o.x = f2bf(v.x * sc); o.y = f2bf(v.y * sc); o.z = f2bf(v.z * sc); o.w = f2bf(v.w * sc);
  *(ushort4*)(h + (size_t)row * HHH + lane * 4) = o;
}

// ---------------------------------------------------------------- K2: Hio = h @ [W_in;W_out]^T + [b_in;b_out]
// GEMM M=32768, N=512, K=256. 128x128 tile, BK=64, global_load_lds staging (bf16 ws sources).
__global__ __launch_bounds__(256) void k_hio(const u16* __restrict__ h,
                                             const u16* __restrict__ wcat,
                                             const float* __restrict__ b_in,
                                             const float* __restrict__ b_out,
                                             u16* __restrict__ Hio) {
  __shared__ __align__(16) u16 Xs[128 * 64];
  __shared__ __align__(16) u16 Ws[128 * 64];
  int m0 = blockIdx.x * 128, n0 = blockIdx.y * 128;
  int t = threadIdx.x, w = t >> 6, lane = t & 63;
  const u16* wbase = wcat + ((n0 < 256) ? (size_t)n0 * 256 : (size_t)65536 + (size_t)(n0 - 256) * 256);
  int wm = w >> 1, wn = w & 1;
  int rsub = lane >> 3, kofs = (lane & 7) * 8;
  f32x4 acc[4][4];
  for (int a = 0; a < 4; ++a) for (int b = 0; b < 4; ++b) acc[a][b] = (f32x4)0.0f;

  for (int kt = 0; kt < 4; ++kt) {
    int k0 = kt * 64;
    for (int i = 0; i < 4; ++i) {
      int r = 32 * w + 8 * i;
      async16(h + (size_t)(m0 + r + rsub) * 256 + k0 + kofs, &Xs[r * 64]);
      async16(wbase + (size_t)(r + rsub) * 256 + k0 + kofs, &Ws[r * 64]);
    }
    __syncthreads();
    for (int ks = 0; ks < 2; ++ks) {
      int kk = ks * 32 + (lane >> 4) * 8;
      bf16x8 af[4], bf[4];
      for (int mt = 0; mt < 4; ++mt)
        af[mt] = *(const bf16x8*)(Xs + (64 * wm + 16 * mt + (lane & 15)) * 64 + kk);
      for (int nt = 0; nt < 4; ++nt)
        bf[nt] = *(const bf16x8*)(Ws + (64 * wn + 16 * nt + (lane & 15)) * 64 + kk);
      for (int mt = 0; mt < 4; ++mt)
        for (int nt = 0; nt < 4; ++nt)
          acc[mt][nt] = __builtin_amdgcn_mfma_f32_16x16x32_bf16(af[mt], bf[nt], acc[mt][nt], 0, 0, 0);
    }
    __syncthreads();
  }
  for (int nt = 0; nt < 4; ++nt) {
    int n = n0 + 64 * wn + 16 * nt + (lane & 15);
    float bv = (n < 256) ? b_in[n] : b_out[n - 256];
    for (int mt = 0; mt < 4; ++mt)
      for (int e = 0; e < 4; ++e) {
        int m = m0 + 64 * wm + 16 * mt + (lane >> 4) * 4 + e;
        Hio[(size_t)m * 512 + n] = f2bf(acc[mt][nt][e] + bv);
      }
  }
}

// ---------------------------------------------------------------- K3: per-batch adjacency matmul
// inp[b][n][c<256]  = sum_m A[b][n][m]    * Hio[b*64+m][c] + b_iah[c]
// inp[b][n][c>=256] = sum_m A[b][n][64+m] * Hio[b*64+m][c] + b_oah[c-256]
__global__ __launch_bounds__(256) void k_amul(const float* __restrict__ Ag,
                                              const u16* __restrict__ Hio,
                                              const float* __restrict__ b_iah,
                                              const float* __restrict__ b_oah,
                                              u16* __restrict__ inp) {
  __shared__ __align__(16) u16 As[64 * 136];   // A[b]: 64 x 128 bf16, pad->136
  __shared__ __align__(16) u16 Hs[64 * 264];   // 64 Hio rows x 256 cols (per half), pad->264
  int b = blockIdx.x;
  int t = threadIdx.x, w = t >> 6, lane = t & 63;
  {
    int r = t >> 2, q = t & 3;   // row 0..63, quarter of 128 cols
    const float4* src = (const float4*)(Ag + (size_t)b * 8192 + r * 128 + q * 32);
    u16* dst = As + r * 136 + q * 32;
    for (int j = 0; j < 8; ++j) {
      float4 v = src[j];
      dst[j * 4 + 0] = f2bf(v.x); dst[j * 4 + 1] = f2bf(v.y);
      dst[j * 4 + 2] = f2bf(v.z); dst[j * 4 + 3] = f2bf(v.w);
    }
  }
  for (int co = 0; co < 2; ++co) {
    __syncthreads();   // A ready / previous compute done
    {
      int r = t >> 2, q = t & 3;
      const uint4* src = (const uint4*)(Hio + ((size_t)b * 64 + r) * 512 + co * 256 + q * 64);
      uint4* dst = (uint4*)(Hs + r * 264 + q * 64);
      for (int j = 0; j < 8; ++j) dst[j] = src[j];
    }
    __syncthreads();
    f32x4 acc[4][4];
    for (int a = 0; a < 4; ++a) for (int c = 0; c < 4; ++c) acc[a][c] = (f32x4)0.0f;
    int khalf = co * 64;  // A_in cols 0..63, A_out cols 64..127
    for (int ks = 0; ks < 2; ++ks) {
      bf16x8 af[4];
      int kk = khalf + ks * 32 + (lane >> 4) * 8;
      for (int mt = 0; mt < 4; ++mt)
        af[mt] = *(const bf16x8*)(As + (16 * mt + (lane & 15)) * 136 + kk);
      int kb = ks * 32 + (lane >> 4) * 8;
      for (int nt = 0; nt < 4; ++nt) {
        int c = w * 64 + 16 * nt + (lane & 15);
        bf16x8 bfr;
        for (int j = 0; j < 8; ++j) bfr[j] = (short)Hs[(kb + j) * 264 + c];  // transposed scalar reads
        for (int mt = 0; mt < 4; ++mt)
          acc[mt][nt] = __builtin_amdgcn_mfma_f32_16x16x32_bf16(af[mt], bfr, acc[mt][nt], 0, 0, 0);
      }
    }
    const float* bias = (co == 0) ? b_iah : b_oah;
    for (int nt = 0; nt < 4; ++nt) {
      int cl = w * 64 + 16 * nt + (lane & 15);
      float bv = bias[cl];
      int cg = co * 256 + cl;
      for (int mt = 0; mt < 4; ++mt)
        for (int e = 0; e < 4; ++e) {
          int rrow = 16 * mt + (lane >> 4) * 4 + e;
          inp[((size_t)b * 64 + rrow) * 512 + cg] = f2bf(acc[mt][nt][e] + bv);
        }
    }
  }
}

// ---------------------------------------------------------------- K4: fused gate GEMM + GRU
// acc[0]=i_r+h_r (K=768), acc[1]=i_i+h_i (K=768), acc[2]=i_n (K=512), acc[3]=h_n (K=256).
// X = [inp | h] per row. Block: 64 rows x 64 gate cols; wave w owns rows 16w..16w+15
// and ALL four groups -> epilogue fully in-wave.
__global__ __launch_bounds__(256) void k_gates(const u16* __restrict__ inp,
                                               const u16* __restrict__ h,
                                               const u16* __restrict__ wcat,
                                               const float* __restrict__ b_ih,
                                               const float* __restrict__ b_hh,
                                               float* __restrict__ out) {
  __shared__ __align__(16) u16 Xs[64 * 64];
  __shared__ __align__(16) u16 Ws[4][64 * 64];
  const u16* wih_b = wcat + 131072;   // w_ih bf16 [768,512]
  const u16* whh_b = wcat + 524288;   // w_hh bf16 [768,256]
  int m0 = blockIdx.x * 64;
  int j0 = blockIdx.y * 64;
  int t = threadIdx.x, w = t >> 6, lane = t & 63;
  int rsub = lane >> 3, kofs = (lane & 7) * 8;
  f32x4 acc[4][4];  // [group][ntile]
  for (int g = 0; g < 4; ++g) for (int nt = 0; nt < 4; ++nt) acc[g][nt] = (f32x4)0.0f;

  for (int kt = 0; kt < 12; ++kt) {
    int k0 = kt * 64;
    bool lo = (kt < 8);          // k<512 -> w_ih / inp half
    int idle = lo ? 3 : 2;       // inactive group's wave stages X
    if (w == idle) {
      const u16* xsrc = lo ? (inp + (size_t)m0 * 512 + k0)
                           : (h   + (size_t)m0 * 256 + (k0 - 512));
      int pitch = lo ? 512 : 256;
      for (int i = 0; i < 8; ++i)
        async16(xsrc + (size_t)(8 * i + rsub) * pitch + kofs, &Xs[(8 * i) * 64]);
    } else {
      int g = w;
      const u16* wsrc; int pitch;
      if (lo) { wsrc = wih_b + (size_t)(g * 256 + j0) * 512 + k0;                          pitch = 512; }
      else    { wsrc = whh_b + (size_t)((g == 3 ? 512 : g * 256) + j0) * 256 + (k0 - 512); pitch = 256; }
      for (int i = 0; i < 8; ++i)
        async16(wsrc + (size_t)(8 * i + rsub) * pitch + kofs, &Ws[g][(8 * i) * 64]);
    }
    __syncthreads();
    int gl = lo ? 2 : 3;
    const int gs[3] = {0, 1, gl};
    for (int ks = 0; ks < 2; ++ks) {
      int kk = ks * 32 + (lane >> 4) * 8;
      bf16x8 af = *(const bf16x8*)(Xs + (16 * w + (lane & 15)) * 64 + kk);
      for (int gg = 0; gg < 3; ++gg) {
        int g = gs[gg];
        for (int nt = 0; nt < 4; ++nt) {
          bf16x8 bfr = *(const bf16x8*)(Ws[g] + (16 * nt + (lane & 15)) * 64 + kk);
          acc[g][nt] = __builtin_amdgcn_mfma_f32_16x16x32_bf16(af, bfr, acc[g][nt], 0, 0, 0);
        }
      }
    }
    __syncthreads();
  }
  // epilogue: GRU gates, in-wave (rows 16w..16w+15), f32 output
  int col = lane & 15;
  int rbase = 16 * w + (lane >> 4) * 4;
  for (int nt = 0; nt < 4; ++nt) {
    int j = j0 + 16 * nt + col;
    float brs = b_ih[j] + b_hh[j];
    float bis = b_ih[256 + j] + b_hh[256 + j];
    float bin = b_ih[512 + j];
    float bhn = b_hh[512 + j];
    for (int e = 0; e < 4; ++e) {
      int m = m0 + rbase + e;
      float r  = sigmoidf_(acc[0][nt][e] + brs);
      float ig = sigmoidf_(acc[1][nt][e] + bis);
      float hn = acc[3][nt][e] + bhn;
      float ng = tanhf(acc[2][nt][e] + bin + r * hn);
      float hv = bf2f(h[(size_t)m * 256 + j]);
      out[(size_t)m * 256 + j] = ng + ig * (hv - ng);
    }
  }
}

extern "C" void kernel_launch(void* const* d_in, const int* in_sizes, int n_in,
                              void* d_out, int out_size, void* d_ws, size_t ws_size,
                              hipStream_t stream) {
  (void)in_sizes; (void)n_in; (void)out_size; (void)ws_size;
  const int*   inputs = (const int*)d_in[0];
  const float* A      = (const float*)d_in[1];
  const float* emb    = (const float*)d_in[2];
  const float* W_in   = (const float*)d_in[3];
  const float* b_in   = (const float*)d_in[4];
  const float* W_out  = (const float*)d_in[5];
  const float* b_out  = (const float*)d_in[6];
  const float* w_ih   = (const float*)d_in[7];
  const float* b_ih   = (const float*)d_in[8];
  const float* w_hh   = (const float*)d_in[9];
  const float* b_hh   = (const float*)d_in[10];
  const float* b_iah  = (const float*)d_in[11];
  const float* b_oah  = (const float*)d_in[12];
  float* out = (float*)d_out;

  u16* h    = (u16*)d_ws;                 // BN*256 bf16 = 16.8 MB
  u16* Hio  = h + (size_t)BN_ * HHH;      // BN*512 bf16 = 33.6 MB
  u16* inp  = Hio + (size_t)BN_ * H2_;    // BN*512 bf16 = 33.6 MB
  u16* wcat = inp + (size_t)BN_ * H2_;    // 720896 bf16 = 1.44 MB (total ~85.3 MB)

  k_convert<<<2816, 256, 0, stream>>>(W_in, W_out, w_ih, w_hh, wcat);
  k_gather_norm<<<BN_ / 4, 256, 0, stream>>>(inputs, emb, h);
  k_hio<<<dim3(BN_ / 128, 4), 256, 0, stream>>>(h, wcat, b_in, b_out, Hio);
  k_amul<<<BB, 256, 0, stream>>>(A, Hio, b_iah, b_oah, inp);
  k_gates<<<dim3(BN_ / 64, 4), 256, 0, stream>>>(inp, h, wcat, b_ih, b_hh, out);
}

// Round 3
// 326.972 us; speedup vs baseline: 1.0282x; 1.0282x over previous
//
#include <hip/hip_runtime.h>
#include <stdint.h>

// Problem dims
#define BB   512
#define NNN  64
#define HHH  256
#define BN_  32768   // B*N
#define H2_  512
#define H3_  768

typedef unsigned short u16;
typedef unsigned int   u32;
typedef __attribute__((ext_vector_type(8))) short bf16x8;   // 8 bf16 in 4 VGPRs
typedef __attribute__((ext_vector_type(4))) float f32x4;

__device__ __forceinline__ u16 f2bf(float f) {
  union { float f; u32 u; } x; x.f = f;
  return (u16)((x.u + 0x7fffu + ((x.u >> 16) & 1u)) >> 16);  // RNE
}
__device__ __forceinline__ float bf2f(u16 v) {
  union { u32 u; float f; } x; x.u = ((u32)v) << 16; return x.f;
}
// async global->LDS, 16B per lane; LDS dest = wave-uniform base + lane*16
__device__ __forceinline__ void async16(const void* g, void* l) {
  __builtin_amdgcn_global_load_lds(
      (const __attribute__((address_space(1))) u32*)(uintptr_t)g,
      (__attribute__((address_space(3))) u32*)(uintptr_t)l, 16, 0, 0);
}
__device__ __forceinline__ float sigmoidf_(float x) { return 1.0f / (1.0f + __expf(-x)); }

// XOR-swizzled element offset into a [rows][64 u16] tile: row r, logical 16B-chunk c.
// Staged via async16 with kofs = ((lane&7)^(lane>>3))*8, so physical chunk = c ^ (r&7).
__device__ __forceinline__ int swz(int r, int c) { return (r << 6) + (((c ^ (r & 7)) << 3)); }

// ---------------------------------------------------------------- K0: f32 weights -> bf16 wcat
// wcat layout (elems): [W_in 65536 | W_out 65536 | w_ih 393216 | w_hh 196608] total 720896
__global__ __launch_bounds__(256) void k_convert(const float* __restrict__ W_in,
                                                 const float* __restrict__ W_out,
                                                 const float* __restrict__ w_ih,
                                                 const float* __restrict__ w_hh,
                                                 u16* __restrict__ wcat) {
  int i = blockIdx.x * 256 + threadIdx.x;
  const float* src; int off;
  if (i < 65536)       { src = W_in;  off = i; }
  else if (i < 131072) { src = W_out; off = i - 65536; }
  else if (i < 524288) { src = w_ih;  off = i - 131072; }
  else                 { src = w_hh;  off = i - 524288; }
  wcat[i] = f2bf(src[off]);
}

// ---------------------------------------------------------------- K1: gather + L2 norm
__global__ __launch_bounds__(256) void k_gather_norm(const int* __restrict__ idx,
                                                     const float* __restrict__ emb,
                                                     u16* __restrict__ h) {
  int row  = blockIdx.x * 4 + (threadIdx.x >> 6);
  int lane = threadIdx.x & 63;
  int e = idx[row];
  float4 v = *(const float4*)(emb + (size_t)e * HHH + lane * 4);
  float s = v.x * v.x + v.y * v.y + v.z * v.z + v.w * v.w;
  for (int off = 32; off; off >>= 1) s += __shfl_xor(s, off, 64);
  float sc = 1.0f / (sqrtf(s) + 1e-12f);
  ushort4 o;
  o.x = f2bf(v.x * sc); o.y = f2bf(v.y * sc); o.z = f2bf(v.z * sc); o.w = f2bf(v.w * sc);
  *(ushort4*)(h + (size_t)row * HHH + lane * 4) = o;
}

// ---------------------------------------------------------------- K2: HioT = wcat @ h^T  (+bias by channel)
// A-op = wcat channel rows (M=512), B-op = h node rows (N=32768), K=256.
// Output HioT[b][c][node]: addr = (n>>6)*32768 + c*64 + (n&63).
__global__ __launch_bounds__(256) void k_hio(const u16* __restrict__ h,
                                             const u16* __restrict__ wcat,
                                             const float* __restrict__ b_in,
                                             const float* __restrict__ b_out,
                                             u16* __restrict__ HioT) {
  __shared__ __align__(16) u16 Ws[128 * 64];   // 128 channels x 64 k
  __shared__ __align__(16) u16 Hs[128 * 64];   // 128 nodes    x 64 k
  int c0 = blockIdx.y * 128;     // channel tile base
  int n0 = blockIdx.x * 128;     // global node tile base
  int t = threadIdx.x, w = t >> 6, lane = t & 63;
  int wm = w >> 1, wn = w & 1;   // wm: channel half, wn: node half
  int rsub = lane >> 3, kofs = ((lane & 7) ^ rsub) << 3;   // swizzled source chunk
  const u16* wbase = wcat + (size_t)c0 * 256;  // wcat stacking => valid for all c in [0,512)
  f32x4 acc[4][4];
  for (int a = 0; a < 4; ++a) for (int b = 0; b < 4; ++b) acc[a][b] = (f32x4)0.0f;

  for (int kt = 0; kt < 4; ++kt) {
    int k0 = kt * 64;
    for (int i = 0; i < 4; ++i) {
      int r = 32 * w + 8 * i;
      async16(wbase + (size_t)(r + rsub) * 256 + k0 + kofs, &Ws[r * 64]);
      async16(h + (size_t)(n0 + r + rsub) * 256 + k0 + kofs, &Hs[r * 64]);
    }
    __syncthreads();
    for (int ks = 0; ks < 2; ++ks) {
      int cidx = ks * 4 + (lane >> 4);
      bf16x8 af[4], bf[4];
      for (int mt = 0; mt < 4; ++mt)
        af[mt] = *(const bf16x8*)(Ws + swz(64 * wm + 16 * mt + (lane & 15), cidx));
      for (int nt = 0; nt < 4; ++nt)
        bf[nt] = *(const bf16x8*)(Hs + swz(64 * wn + 16 * nt + (lane & 15), cidx));
      for (int mt = 0; mt < 4; ++mt)
        for (int nt = 0; nt < 4; ++nt)
          acc[mt][nt] = __builtin_amdgcn_mfma_f32_16x16x32_bf16(af[mt], bf[nt], acc[mt][nt], 0, 0, 0);
    }
    __syncthreads();
  }
  for (int mt = 0; mt < 4; ++mt)
    for (int e = 0; e < 4; ++e) {
      int c = c0 + 64 * wm + 16 * mt + (lane >> 4) * 4 + e;
      float bv = (c < 256) ? b_in[c] : b_out[c - 256];
      for (int nt = 0; nt < 4; ++nt) {
        int n = n0 + 64 * wn + 16 * nt + (lane & 15);
        HioT[(size_t)(n >> 6) * 32768 + (size_t)c * 64 + (n & 63)] = f2bf(acc[mt][nt][e] + bv);
      }
    }
}

// ---------------------------------------------------------------- K3: per-batch adjacency matmul
// inp[node][c + co*256] = sum_m A[node][m + co*64] * HioT[c][m] + bias[c]
__global__ __launch_bounds__(256) void k_amul(const float* __restrict__ Ag,
                                              const u16* __restrict__ HioT,
                                              const float* __restrict__ b_iah,
                                              const float* __restrict__ b_oah,
                                              u16* __restrict__ inp) {
  __shared__ __align__(16) u16 As[64 * 136];   // A[b]: 64 x 128 bf16, pad->136
  __shared__ __align__(16) u16 Hs[256 * 64];   // HioT[b] half: 256 ch x 64 nodes (swizzled)
  int b = blockIdx.x;
  int t = threadIdx.x, w = t >> 6, lane = t & 63;
  int rsub = lane >> 3, kofs = ((lane & 7) ^ rsub) << 3;
  {
    int r = t >> 2, q = t & 3;   // row 0..63, quarter of 128 cols
    const float4* src = (const float4*)(Ag + (size_t)b * 8192 + r * 128 + q * 32);
    u16* dst = As + r * 136 + q * 32;
    for (int j = 0; j < 8; ++j) {
      float4 v = src[j];
      ushort4 o;
      o.x = f2bf(v.x); o.y = f2bf(v.y); o.z = f2bf(v.z); o.w = f2bf(v.w);
      *(ushort4*)(dst + j * 4) = o;
    }
  }
  for (int co = 0; co < 2; ++co) {
    __syncthreads();   // As ready / previous compute done
    for (int i = 0; i < 2; ++i) {
      int rb = 64 * w + 32 * i;   // stage 256 rows: 64/wave, 8 rows per async16
      for (int s = 0; s < 4; ++s)
        async16(HioT + (size_t)b * 32768 + (size_t)(co * 256 + rb + 8 * s + rsub) * 64 + kofs,
                &Hs[(rb + 8 * s) * 64]);
    }
    __syncthreads();
    f32x4 acc[4][4];
    for (int a = 0; a < 4; ++a) for (int c = 0; c < 4; ++c) acc[a][c] = (f32x4)0.0f;
    int khalf = co * 64;  // A_in cols 0..63, A_out cols 64..127
    for (int ks = 0; ks < 2; ++ks) {
      int cidx = ks * 4 + (lane >> 4);
      int kk = khalf + ks * 32 + (lane >> 4) * 8;
      bf16x8 af[4];
      for (int mt = 0; mt < 4; ++mt)
        af[mt] = *(const bf16x8*)(As + (16 * mt + (lane & 15)) * 136 + kk);
      for (int nt = 0; nt < 4; ++nt) {
        int cl = w * 64 + 16 * nt + (lane & 15);
        bf16x8 bfr = *(const bf16x8*)(Hs + swz(cl, cidx));
        for (int mt = 0; mt < 4; ++mt)
          acc[mt][nt] = __builtin_amdgcn_mfma_f32_16x16x32_bf16(af[mt], bfr, acc[mt][nt], 0, 0, 0);
      }
    }
    const float* bias = (co == 0) ? b_iah : b_oah;
    for (int nt = 0; nt < 4; ++nt) {
      int cl = w * 64 + 16 * nt + (lane & 15);
      float bv = bias[cl];
      int cg = co * 256 + cl;
      for (int mt = 0; mt < 4; ++mt)
        for (int e = 0; e < 4; ++e) {
          int rrow = 16 * mt + (lane >> 4) * 4 + e;
          inp[((size_t)b * 64 + rrow) * 512 + cg] = f2bf(acc[mt][nt][e] + bv);
        }
    }
  }
}

// ---------------------------------------------------------------- K4: fused gate GEMM + GRU
// acc[g][mt]: g0=i_r+h_r (K=768), g1=i_i+h_i (K=768), g2=i_n (K=512), g3=h_n (K=256).
// Block 64 rows x 64 gate-cols. Wave w owns cols 16w..16w+15 and ALL 64 rows:
// B-frag read amortized over 4 m-tiles (MFMA:read = 24:14 per kt).
__global__ __launch_bounds__(256) void k_gates(const u16* __restrict__ inp,
                                               const u16* __restrict__ h,
                                               const u16* __restrict__ wcat,
                                               const float* __restrict__ b_ih,
                                               const float* __restrict__ b_hh,
                                               float* __restrict__ out) {
  __shared__ __align__(16) u16 Xs[64 * 64];
  __shared__ __align__(16) u16 Ws[4][64 * 64];
  const u16* wih_b = wcat + 131072;   // w_ih bf16 [768,512]
  const u16* whh_b = wcat + 524288;   // w_hh bf16 [768,256]
  int m0 = blockIdx.x * 64;
  int j0 = blockIdx.y * 64;
  int t = threadIdx.x, w = t >> 6, lane = t & 63;
  int rsub = lane >> 3, kofs = ((lane & 7) ^ rsub) << 3;
  f32x4 acc[4][4];  // [group][mtile]
  for (int g = 0; g < 4; ++g) for (int mt = 0; mt < 4; ++mt) acc[g][mt] = (f32x4)0.0f;

  for (int kt = 0; kt < 12; ++kt) {
    int k0 = kt * 64;
    bool lo = (kt < 8);          // k<512 -> w_ih / inp half
    int idle = lo ? 3 : 2;       // inactive group's wave stages X
    if (w == idle) {
      const u16* xsrc = lo ? (inp + (size_t)m0 * 512 + k0)
                           : (h   + (size_t)m0 * 256 + (k0 - 512));
      int pitch = lo ? 512 : 256;
      for (int i = 0; i < 8; ++i)
        async16(xsrc + (size_t)(8 * i + rsub) * pitch + kofs, &Xs[(8 * i) * 64]);
    } else {
      int g = w;
      const u16* wsrc; int pitch;
      if (lo) { wsrc = wih_b + (size_t)(g * 256 + j0) * 512 + k0;                          pitch = 512; }
      else    { wsrc = whh_b + (size_t)((g == 3 ? 512 : g * 256) + j0) * 256 + (k0 - 512); pitch = 256; }
      for (int i = 0; i < 8; ++i)
        async16(wsrc + (size_t)(8 * i + rsub) * pitch + kofs, &Ws[g][(8 * i) * 64]);
    }
    __syncthreads();
    int gl = lo ? 2 : 3;
    const int gs[3] = {0, 1, gl};
    for (int ks = 0; ks < 2; ++ks) {
      int cidx = ks * 4 + (lane >> 4);
      bf16x8 af[4];
      for (int mt = 0; mt < 4; ++mt)
        af[mt] = *(const bf16x8*)(Xs + swz(16 * mt + (lane & 15), cidx));
      for (int gg = 0; gg < 3; ++gg) {
        int g = gs[gg];
        bf16x8 bfr = *(const bf16x8*)(Ws[g] + swz(16 * w + (lane & 15), cidx));
        for (int mt = 0; mt < 4; ++mt)
          acc[g][mt] = __builtin_amdgcn_mfma_f32_16x16x32_bf16(af[mt], bfr, acc[g][mt], 0, 0, 0);
      }
    }
    __syncthreads();
  }
  // epilogue: GRU gates; wave w owns col j for all 64 rows
  int j = j0 + 16 * w + (lane & 15);
  float brs = b_ih[j] + b_hh[j];
  float bis = b_ih[256 + j] + b_hh[256 + j];
  float bin = b_ih[512 + j];
  float bhn = b_hh[512 + j];
  for (int mt = 0; mt < 4; ++mt)
    for (int e = 0; e < 4; ++e) {
      int m = m0 + 16 * mt + (lane >> 4) * 4 + e;
      float r  = sigmoidf_(acc[0][mt][e] + brs);
      float ig = sigmoidf_(acc[1][mt][e] + bis);
      float hn = acc[3][mt][e] + bhn;
      float ng = tanhf(acc[2][mt][e] + bin + r * hn);
      float hv = bf2f(h[(size_t)m * 256 + j]);
      out[(size_t)m * 256 + j] = ng + ig * (hv - ng);
    }
}

extern "C" void kernel_launch(void* const* d_in, const int* in_sizes, int n_in,
                              void* d_out, int out_size, void* d_ws, size_t ws_size,
                              hipStream_t stream) {
  (void)in_sizes; (void)n_in; (void)out_size; (void)ws_size;
  const int*   inputs = (const int*)d_in[0];
  const float* A      = (const float*)d_in[1];
  const float* emb    = (const float*)d_in[2];
  const float* W_in   = (const float*)d_in[3];
  const float* b_in   = (const float*)d_in[4];
  const float* W_out  = (const float*)d_in[5];
  const float* b_out  = (const float*)d_in[6];
  const float* w_ih   = (const float*)d_in[7];
  const float* b_ih   = (const float*)d_in[8];
  const float* w_hh   = (const float*)d_in[9];
  const float* b_hh   = (const float*)d_in[10];
  const float* b_iah  = (const float*)d_in[11];
  const float* b_oah  = (const float*)d_in[12];
  float* out = (float*)d_out;

  u16* h    = (u16*)d_ws;                 // BN*256 bf16 = 16.8 MB
  u16* HioT = h + (size_t)BN_ * HHH;      // 512*512*64 bf16 = 33.6 MB
  u16* inp  = HioT + (size_t)BN_ * H2_;   // BN*512 bf16 = 33.6 MB
  u16* wcat = inp + (size_t)BN_ * H2_;    // 720896 bf16 = 1.44 MB

  k_convert<<<2816, 256, 0, stream>>>(W_in, W_out, w_ih, w_hh, wcat);
  k_gather_norm<<<BN_ / 4, 256, 0, stream>>>(inputs, emb, h);
  k_hio<<<dim3(BN_ / 128, 4), 256, 0, stream>>>(h, wcat, b_in, b_out, HioT);
  k_amul<<<BB, 256, 0, stream>>>(A, HioT, b_iah, b_oah, inp);
  k_gates<<<dim3(BN_ / 64, 4), 256, 0, stream>>>(inp, h, wcat, b_ih, b_hh, out);
}

// Round 7
// 277.790 us; speedup vs baseline: 1.2102x; 1.1770x over previous
//
#include <hip/hip_runtime.h>
#include <stdint.h>

// Problem dims
#define BB   512
#define NNN  64
#define HHH  256
#define BN_  32768   // B*N
#define H2_  512
#define H3_  768

typedef unsigned short u16;
typedef unsigned int   u32;
typedef __attribute__((ext_vector_type(8)))  short bf16x8;   // 8 bf16 in 4 VGPRs
typedef __attribute__((ext_vector_type(4)))  float f32x4;
typedef __attribute__((ext_vector_type(16))) float f32x16;

__device__ __forceinline__ u16 f2bf(float f) {
  union { float f; u32 u; } x; x.f = f;
  return (u16)((x.u + 0x7fffu + ((x.u >> 16) & 1u)) >> 16);  // RNE
}
__device__ __forceinline__ float bf2f(u16 v) {
  union { u32 u; float f; } x; x.u = ((u32)v) << 16; return x.f;
}
__device__ __forceinline__ void async16(const void* g, void* l) {
  __builtin_amdgcn_global_load_lds(
      (const __attribute__((address_space(1))) u32*)(uintptr_t)g,
      (__attribute__((address_space(3))) u32*)(uintptr_t)l, 16, 0, 0);
}
__device__ __forceinline__ float sigmoidf_(float x) { return 1.0f / (1.0f + __expf(-x)); }
__device__ __forceinline__ float tanhf_(float x)    { return 2.0f / (1.0f + __expf(-2.0f * x)) - 1.0f; }

// ---------------------------------------------------------------- K0: f32 weights -> bf16 wcat
// wcat layout (elems): [W_in 65536 | W_out 65536 | w_ih 393216 | w_hh 196608]
__global__ __launch_bounds__(256) void k_convert(const float* __restrict__ W_in,
                                                 const float* __restrict__ W_out,
                                                 const float* __restrict__ w_ih,
                                                 const float* __restrict__ w_hh,
                                                 u16* __restrict__ wcat) {
  int i = blockIdx.x * 256 + threadIdx.x;
  const float* src; int off;
  if (i < 65536)       { src = W_in;  off = i; }
  else if (i < 131072) { src = W_out; off = i - 65536; }
  else if (i < 524288) { src = w_ih;  off = i - 131072; }
  else                 { src = w_hh;  off = i - 524288; }
  wcat[i] = f2bf(src[off]);
}

// ---------------------------------------------------------------- K1: gather + L2 norm
__global__ __launch_bounds__(256) void k_gather_norm(const int* __restrict__ idx,
                                                     const float* __restrict__ emb,
                                                     u16* __restrict__ h) {
  int row  = blockIdx.x * 4 + (threadIdx.x >> 6);
  int lane = threadIdx.x & 63;
  int e = idx[row];
  float4 v = *(const float4*)(emb + (size_t)e * HHH + lane * 4);
  float s = v.x * v.x + v.y * v.y + v.z * v.z + v.w * v.w;
  for (int off = 32; off; off >>= 1) s += __shfl_xor(s, off, 64);
  float sc = 1.0f / (sqrtf(s) + 1e-12f);
  ushort4 o;
  o.x = f2bf(v.x * sc); o.y = f2bf(v.y * sc); o.z = f2bf(v.z * sc); o.w = f2bf(v.w * sc);
  *(ushort4*)(h + (size_t)row * HHH + lane * 4) = o;
}

// ---------------------------------------------------------------- K2: HioT = wcat @ h^T (+bias)
// A-op = h node rows (M), B-op = wcat channel rows (N) -> C[node][ch]; epilogue transposes
// through LDS so HBM stores are 16B/lane coalesced. HioT[b][c][node64].
__global__ __launch_bounds__(256) void k_hio(const u16* __restrict__ h,
                                             const u16* __restrict__ wcat,
                                             const float* __restrict__ b_in,
                                             const float* __restrict__ b_out,
                                             u16* __restrict__ HioT) {
  __shared__ __align__(16) char smem[34816];         // phase1: Ws 16K | Hs 16K ; phase2: Tt [128][136] u16
  u16* Ws = (u16*)smem;
  u16* Hs = Ws + 8192;
  u16* Tt = (u16*)smem;
  int c0 = blockIdx.y * 128;
  int n0 = blockIdx.x * 128;
  int t = threadIdx.x, w = t >> 6, lane = t & 63;
  int wm = w >> 1, wn = w & 1;    // wm: node half, wn: channel half
  int rsub = lane >> 3, kofs = ((lane & 7) ^ rsub) << 3;
  const u16* wbase = wcat + (size_t)c0 * 256;
  f32x4 acc[4][4];   // [node-tile][ch-tile]
  for (int a = 0; a < 4; ++a) for (int b = 0; b < 4; ++b) acc[a][b] = (f32x4)0.0f;

  for (int kt = 0; kt < 4; ++kt) {
    int k0 = kt * 64;
    for (int i = 0; i < 4; ++i) {
      int r = 32 * w + 8 * i;
      async16(wbase + (size_t)(r + rsub) * 256 + k0 + kofs, &Ws[r * 64]);
      async16(h + (size_t)(n0 + r + rsub) * 256 + k0 + kofs, &Hs[r * 64]);
    }
    __syncthreads();
    for (int ks = 0; ks < 2; ++ks) {
      int c = ks * 4 + (lane >> 4);
      bf16x8 af[4], bf[4];
      for (int mt = 0; mt < 4; ++mt) {
        int r = 64 * wm + 16 * mt + (lane & 15);
        af[mt] = *(const bf16x8*)(Hs + r * 64 + ((c ^ (r & 7)) << 3));
      }
      for (int nt = 0; nt < 4; ++nt) {
        int r = 64 * wn + 16 * nt + (lane & 15);
        bf[nt] = *(const bf16x8*)(Ws + r * 64 + ((c ^ (r & 7)) << 3));
      }
      for (int mt = 0; mt < 4; ++mt)
        for (int nt = 0; nt < 4; ++nt)
          acc[mt][nt] = __builtin_amdgcn_mfma_f32_16x16x32_bf16(af[mt], bf[nt], acc[mt][nt], 0, 0, 0);
    }
    __syncthreads();
  }
  // epilogue: bias + pack 4 consecutive nodes per b64 into Tt[ch][node(pad 136)]
  for (int nt = 0; nt < 4; ++nt) {
    int chl = 64 * wn + 16 * nt + (lane & 15);
    int cg = c0 + chl;
    float bv = (cg < 256) ? b_in[cg] : b_out[cg - 256];
    for (int mt = 0; mt < 4; ++mt) {
      int nb = 64 * wm + 16 * mt + (lane >> 4) * 4;
      u32 lo = (u32)f2bf(acc[mt][nt][0] + bv) | ((u32)f2bf(acc[mt][nt][1] + bv) << 16);
      u32 hi = (u32)f2bf(acc[mt][nt][2] + bv) | ((u32)f2bf(acc[mt][nt][3] + bv) << 16);
      *(uint2*)(Tt + chl * 136 + nb) = make_uint2(lo, hi);
    }
  }
  __syncthreads();
  // coalesced store: 8 iters, 16B per thread
  for (int it = 0; it < 8; ++it) {
    int id = it * 256 + t;                 // [128 ch][2 nblk][8 chunk]
    int ch = id >> 4, nb = (id >> 3) & 1, c8 = id & 7;
    uint4 v = *(const uint4*)(Tt + ch * 136 + nb * 64 + c8 * 8);
    *(uint4*)(HioT + (size_t)((n0 >> 6) + nb) * 32768 + (size_t)(c0 + ch) * 64 + c8 * 8) = v;
  }
}

// ---------------------------------------------------------------- K3: per-batch adjacency matmul
// A-op = HioT channel rows (M), B-op = A node rows (N) -> C[ch][node]; reg-quads pack 4
// consecutive ch -> LDS transpose -> coalesced 16B stores of inp[node][ch].
__global__ __launch_bounds__(256) void k_amul(const float* __restrict__ Ag,
                                              const u16* __restrict__ HioT,
                                              const float* __restrict__ b_iah,
                                              const float* __restrict__ b_oah,
                                              u16* __restrict__ inp) {
  __shared__ __align__(16) u16 As[64 * 136];   // A[b]: 64 x 128 bf16, pad->136
  __shared__ __align__(16) u16 Hs[256 * 64];   // phase: HioT half (swz) ; then Tt2 [64 node][256 ch] xor16B
  int b = blockIdx.x;
  int t = threadIdx.x, w = t >> 6, lane = t & 63;
  int rsub = lane >> 3, kofs = ((lane & 7) ^ rsub) << 3;
  {
    int r = t >> 2, q = t & 3;
    const float4* src = (const float4*)(Ag + (size_t)b * 8192 + r * 128 + q * 32);
    u16* dst = As + r * 136 + q * 32;
    for (int j = 0; j < 8; ++j) {
      float4 v = src[j];
      ushort4 o;
      o.x = f2bf(v.x); o.y = f2bf(v.y); o.z = f2bf(v.z); o.w = f2bf(v.w);
      *(ushort4*)(dst + j * 4) = o;
    }
  }
  for (int co = 0; co < 2; ++co) {
    __syncthreads();
    for (int i = 0; i < 2; ++i) {
      int rb = 64 * w + 32 * i;
      for (int s = 0; s < 4; ++s)
        async16(HioT + (size_t)b * 32768 + (size_t)(co * 256 + rb + 8 * s + rsub) * 64 + kofs,
                &Hs[(rb + 8 * s) * 64]);
    }
    __syncthreads();
    f32x4 acc[4][4];   // [ch-tile][node-tile]
    for (int a = 0; a < 4; ++a) for (int c = 0; c < 4; ++c) acc[a][c] = (f32x4)0.0f;
    for (int ks = 0; ks < 2; ++ks) {
      int c = ks * 4 + (lane >> 4);            // node-chunk
      int kk = co * 64 + ks * 32 + (lane >> 4) * 8;
      bf16x8 af[4], bf[4];
      for (int mt = 0; mt < 4; ++mt) {
        int r = 64 * w + 16 * mt + (lane & 15);   // ch row (within 256-half)
        af[mt] = *(const bf16x8*)(Hs + r * 64 + ((c ^ (r & 7)) << 3));
      }
      for (int nt = 0; nt < 4; ++nt) {
        int n = 16 * nt + (lane & 15);
        bf[nt] = *(const bf16x8*)(As + n * 136 + kk);
      }
      for (int mt = 0; mt < 4; ++mt)
        for (int nt = 0; nt < 4; ++nt)
          acc[mt][nt] = __builtin_amdgcn_mfma_f32_16x16x32_bf16(af[mt], bf[nt], acc[mt][nt], 0, 0, 0);
    }
    __syncthreads();   // done reading Hs; reuse as Tt2
    const float* bias = (co == 0) ? b_iah : b_oah;
    u16* Tt2 = Hs;     // [64 node][256 ch], 16B-chunk xor swizzle by (node&7)
    for (int mt = 0; mt < 4; ++mt) {
      int chb = 64 * w + 16 * mt + (lane >> 4) * 4;
      float b0 = bias[chb], b1 = bias[chb + 1], b2 = bias[chb + 2], b3 = bias[chb + 3];
      for (int nt = 0; nt < 4; ++nt) {
        int node = 16 * nt + (lane & 15);
        u32 lo = (u32)f2bf(acc[mt][nt][0] + b0) | ((u32)f2bf(acc[mt][nt][1] + b1) << 16);
        u32 hi = (u32)f2bf(acc[mt][nt][2] + b2) | ((u32)f2bf(acc[mt][nt][3] + b3) << 16);
        int byte = node * 512 + (((chb >> 3) ^ (node & 7)) << 4) + (chb & 7) * 2;
        *(uint2*)((char*)Tt2 + byte) = make_uint2(lo, hi);
      }
    }
    __syncthreads();
    for (int it = 0; it < 8; ++it) {
      int id = it * 256 + t;                 // [64 node][32 chunk16B]
      int node = id >> 5, c = id & 31;
      uint4 v = *(const uint4*)((char*)Tt2 + node * 512 + ((c ^ (node & 7)) << 4));
      *(uint4*)(inp + ((size_t)b * 64 + node) * 512 + co * 256 + c * 8) = v;
    }
  }
}

// ---------------------------------------------------------------- K4: fused gate GEMM + GRU (32x32x16)
// acc[g][mt]: g0=i_r+h_r (K=768), g1=i_i+h_i (K=768), g2=i_n (K=512), g3=h_n (K=256).
// Block 64 rows x 128 gate-cols; wave w owns cols 32w..32w+31, rows all 64 (2 m-tiles).
// Static LDS = 8K (Xs) + 48K (Wslab) = 56K <= 64K runtime cap. Hh aliases Wslab slab 2
// (free after the K-loop); F f32[64][128] aliases slabs 0-1. kt-loop rolled.
__global__ __launch_bounds__(256, 2) void k_gates(const u16* __restrict__ inp,
                                                  const u16* __restrict__ h,
                                                  const u16* __restrict__ wcat,
                                                  const float* __restrict__ b_ih,
                                                  const float* __restrict__ b_hh,
                                                  float* __restrict__ out) {
  __shared__ __align__(16) u16 Xs[64 * 64];          // 8 KB
  __shared__ __align__(16) u16 Wslab[3 * 128 * 64];  // 48 KB (3 slabs of 16 KB)
  const u16* wih_b = wcat + 131072;   // [768,512]
  const u16* whh_b = wcat + 524288;   // [768,256]
  int m0 = blockIdx.x * 64;
  int j0 = blockIdx.y * 128;
  int t = threadIdx.x, w = t >> 6, lane = t & 63;
  int rsub8 = lane >> 3, kofs8 = ((lane & 7) ^ rsub8) << 3;
  f32x16 acc[4][2];
  for (int g = 0; g < 4; ++g) for (int mt = 0; mt < 2; ++mt) acc[g][mt] = (f32x16)0.0f;

#pragma unroll 1
  for (int kt = 0; kt < 12; ++kt) {
    bool lo = (kt < 8);
    int k0 = lo ? kt * 64 : (kt - 8) * 64;
    const u16* wb = lo ? wih_b : whh_b;
    int wp = lo ? 512 : 256;
    const u16* xb = lo ? (inp + (size_t)m0 * 512 + kt * 64)
                       : (h   + (size_t)m0 * 256 + (kt - 8) * 64);
    int xp = lo ? 512 : 256;
    // 56 async16 ops: 8 X + 3x16 W; wave w takes og = 4i+w (wave-uniform -> uniform branch)
    for (int i = 0; i < 14; ++i) {
      int og = i * 4 + w;
      if (og < 8) {
        async16(xb + (size_t)(og * 8 + rsub8) * xp + kofs8, &Xs[og * 8 * 64]);
      } else {
        int s = (og - 8) >> 4, seg = (og - 8) & 15;
        int jrow = j0 + s * 256 + seg * 8 + rsub8;
        async16(wb + (size_t)jrow * wp + k0 + kofs8, &Wslab[s * 8192 + seg * 8 * 64]);
      }
    }
    __syncthreads();
    int gl = lo ? 2 : 3;
    for (int ks = 0; ks < 4; ++ks) {
      int c = ks * 2 + (lane >> 5);
      bf16x8 af[2];
      for (int mt = 0; mt < 2; ++mt) {
        int r = 32 * mt + (lane & 31);
        af[mt] = *(const bf16x8*)(Xs + r * 64 + ((c ^ (r & 7)) << 3));
      }
      int rB = 32 * w + (lane & 31);
      int aB = rB * 64 + ((c ^ (rB & 7)) << 3);
      for (int s = 0; s < 3; ++s) {
        bf16x8 bfr = *(const bf16x8*)(Wslab + s * 8192 + aB);
        int g = (s < 2) ? s : gl;
        acc[g][0] = __builtin_amdgcn_mfma_f32_32x32x16_bf16(af[0], bfr, acc[g][0], 0, 0, 0);
        acc[g][1] = __builtin_amdgcn_mfma_f32_32x32x16_bf16(af[1], bfr, acc[g][1], 0, 0, 0);
      }
    }
    __syncthreads();
  }
  // stage h tile [64][128] into Wslab slab 2 (free after loop-end barrier)
  u16* Hh = Wslab + 2 * 8192;
  {
    int rsub4 = lane >> 4, cch = lane & 15;
    for (int i = 0; i < 4; ++i) {
      int og = i * 4 + w, r0 = og * 4;
      int kofsH = ((cch ^ ((r0 & 4) | rsub4)) << 3);
      async16(h + (size_t)(m0 + r0 + rsub4) * 256 + j0 + kofsH, &Hh[r0 * 128]);
    }
  }
  __syncthreads();
  // gates in-register; hv from Hh; hy -> F f32[64][128] (aliases Wslab slabs 0-1)
  float* F = (float*)Wslab;
  int jl = 32 * w + (lane & 31);
  int j = j0 + jl;
  float brs = b_ih[j] + b_hh[j];
  float bis = b_ih[256 + j] + b_hh[256 + j];
  float bin = b_ih[512 + j];
  float bhn = b_hh[512 + j];
  int jc = jl >> 3, je = (jl & 7) * 2;
  for (int mt = 0; mt < 2; ++mt)
    for (int e = 0; e < 16; ++e) {
      int row = (e & 3) + 8 * (e >> 2) + 4 * (lane >> 5);
      int mloc = 32 * mt + row;
      float r  = sigmoidf_(acc[0][mt][e] + brs);
      float ig = sigmoidf_(acc[1][mt][e] + bis);
      float hn = acc[3][mt][e] + bhn;
      float ng = tanhf_(acc[2][mt][e] + bin + r * hn);
      float hv = bf2f(*(const u16*)((char*)Hh + mloc * 256 + ((jc ^ (mloc & 7)) << 4) + je));
      F[mloc * 128 + jl] = ng + ig * (hv - ng);
    }
  __syncthreads();
  for (int it = 0; it < 16; ++it) {
    int id = it * 256 + t;            // [64 m][64 j-pairs]
    int mloc = id >> 6, jp = (id & 63) * 2;
    float2 v = *(const float2*)(F + mloc * 128 + jp);
    *(float2*)(out + (size_t)(m0 + mloc) * 256 + j0 + jp) = v;
  }
}

extern "C" void kernel_launch(void* const* d_in, const int* in_sizes, int n_in,
                              void* d_out, int out_size, void* d_ws, size_t ws_size,
                              hipStream_t stream) {
  (void)in_sizes; (void)n_in; (void)out_size; (void)ws_size;
  const int*   inputs = (const int*)d_in[0];
  const float* A      = (const float*)d_in[1];
  const float* emb    = (const float*)d_in[2];
  const float* W_in   = (const float*)d_in[3];
  const float* b_in   = (const float*)d_in[4];
  const float* W_out  = (const float*)d_in[5];
  const float* b_out  = (const float*)d_in[6];
  const float* w_ih   = (const float*)d_in[7];
  const float* b_ih   = (const float*)d_in[8];
  const float* w_hh   = (const float*)d_in[9];
  const float* b_hh   = (const float*)d_in[10];
  const float* b_iah  = (const float*)d_in[11];
  const float* b_oah  = (const float*)d_in[12];
  float* out = (float*)d_out;

  u16* h    = (u16*)d_ws;                 // BN*256 bf16 = 16.8 MB
  u16* HioT = h + (size_t)BN_ * HHH;      // 33.6 MB
  u16* inp  = HioT + (size_t)BN_ * H2_;   // 33.6 MB
  u16* wcat = inp + (size_t)BN_ * H2_;    // 1.44 MB

  k_convert<<<2816, 256, 0, stream>>>(W_in, W_out, w_ih, w_hh, wcat);
  k_gather_norm<<<BN_ / 4, 256, 0, stream>>>(inputs, emb, h);
  k_hio<<<dim3(BN_ / 128, 4), 256, 0, stream>>>(h, wcat, b_in, b_out, HioT);
  k_amul<<<BB, 256, 0, stream>>>(A, HioT, b_iah, b_oah, inp);
  k_gates<<<dim3(BN_ / 64, 2), 256, 0, stream>>>(inp, h, wcat, b_ih, b_hh, out);
}